// Round 10
// baseline (827.130 us; speedup 1.0000x reference)
//
#include <hip/hip_runtime.h>
#include <hip/hip_bf16.h>
#include <cstdint>

// Problem: B_=2048 windows, N=64 tokens, C=512, H=16 heads, hd=32, nW=64.
// Pipeline: k_wprep, k_xprep -> 4x { k_qkv (256^2, BK=32, 4-buf ring, vmcnt(12))
//                                    -> k_attn } -> k_proj (same GEMM skeleton).
typedef __bf16 bf16;
typedef __bf16 bf16x8_t __attribute__((ext_vector_type(8)));
typedef __bf16 bf16x4_t __attribute__((ext_vector_type(4)));
typedef float  f32x4_t  __attribute__((ext_vector_type(4)));

#define MFMA16(a, b, c) __builtin_amdgcn_mfma_f32_16x16x32_bf16((a), (b), (c), 0, 0, 0)

__device__ __forceinline__ void gload_lds16(const bf16* g, bf16* l) {
    __builtin_amdgcn_global_load_lds(
        (const __attribute__((address_space(1))) void*)g,
        (__attribute__((address_space(3))) void*)l,
        16, 0, 0);
}

// ---------------------------------------------------------------------------
// Kernel 1: convert weights to bf16 (qkv_w 1536x512, proj_w 512x512)
// ---------------------------------------------------------------------------
__global__ void k_wprep(const float* __restrict__ wq, const float* __restrict__ wp,
                        bf16* __restrict__ wqb, bf16* __restrict__ wpb) {
    int t = blockIdx.x * 256 + threadIdx.x;
    int stride = gridDim.x * 256;
    for (int i = t; i < 196608; i += stride) {
        float4 v = ((const float4*)wq)[i];
        bf16x4_t o; o[0]=(bf16)v.x; o[1]=(bf16)v.y; o[2]=(bf16)v.z; o[3]=(bf16)v.w;
        ((bf16x4_t*)wqb)[i] = o;
    }
    for (int i = t; i < 65536; i += stride) {
        float4 v = ((const float4*)wp)[i];
        bf16x4_t o; o[0]=(bf16)v.x; o[1]=(bf16)v.y; o[2]=(bf16)v.z; o[3]=(bf16)v.w;
        ((bf16x4_t*)wpb)[i] = o;
    }
}

// ---------------------------------------------------------------------------
// Kernel 2: xp[131072][512] = bf16(x + pe)  (one shot, memory-bound)
// ---------------------------------------------------------------------------
__global__ void k_xprep(const float* __restrict__ x, const float* __restrict__ pe,
                        bf16* __restrict__ xp) {
    int t = blockIdx.x * 256 + threadIdx.x;
    int stride = gridDim.x * 256;
    for (int i = t; i < 8388608; i += stride) {
        int row = i >> 6;
        int g   = (i & 63) * 8;
        const float* xr = x  + ((size_t)row << 9) + g;
        const float* pr = pe + ((size_t)(row & 63) << 9) + g;
        float4 x0 = *(const float4*)(xr);
        float4 x1 = *(const float4*)(xr + 4);
        float4 p0 = *(const float4*)(pr);
        float4 p1 = *(const float4*)(pr + 4);
        bf16x8_t v;
        v[0]=(bf16)(x0.x+p0.x); v[1]=(bf16)(x0.y+p0.y);
        v[2]=(bf16)(x0.z+p0.z); v[3]=(bf16)(x0.w+p0.w);
        v[4]=(bf16)(x1.x+p1.x); v[5]=(bf16)(x1.y+p1.y);
        v[6]=(bf16)(x1.z+p1.z); v[7]=(bf16)(x1.w+p1.w);
        *(bf16x8_t*)(xp + (size_t)i * 8) = v;
    }
}

// ---------------------------------------------------------------------------
// Kernel 3: QKV GEMM over one 32768-row chunk. 256x256 tile, BK=32, 8 waves.
// 4-buffer LDS ring, stage(kt+3) per iter (4 gload_lds/wave), counted
// vmcnt(12) -> 3 iterations (~1000 cyc) of load-latency cover. LDS layout
// [row][32] with piece swizzle ph = lg ^ (row&3): b128 reads at the 8-cyc
// floor (verified slot spread), gload source gp = (lane&3)^((lane>>2)&3).
// Output head-major per chunk: [3][16][512 win][64 tok][32 d] bf16.
// ---------------------------------------------------------------------------
__global__ __launch_bounds__(512, 2) void k_qkv(
    const bf16*  __restrict__ A,     // chunk xp: (32768, 512) bf16
    const bf16*  __restrict__ Bw,    // (1536, 512) bf16
    const float* __restrict__ bias,  // (1536,) f32
    bf16* __restrict__ Cq)           // chunk out, head-major (100.7 MB)
{
    __shared__ bf16 As[4][256 * 32]; // 16 KB per buffer
    __shared__ bf16 Bs[4][256 * 32];
    // LDS 131,072 B -> 1 block/CU (8 waves)

    const int tid  = threadIdx.x;
    const int lane = tid & 63;
    const int wave = tid >> 6;
    const int lr = lane & 15, lg = lane >> 4;
    const int wr = wave >> 2;            // 0..1 : 128-row half
    const int wc = wave & 3;             // 0..3 : 64-col quarter
    const int bid = blockIdx.x;          // 0..767 (= 8 * 96) per chunk
    const int wg  = (bid & 7) * 96 + (bid >> 3);  // XCD-contiguous
    const int mb  = wg / 6, nb = wg - mb * 6;     // 128 x 6
    const size_t m0 = (size_t)mb * 256;
    const int n0 = nb * 256;

    const int srow = lane >> 2;          // staging: row-within-16
    const int sgp  = (lane & 3) ^ (srow & 3);  // pre-swizzled source piece

    f32x4_t acc[8][4] = {};

    auto stage = [&](int kt, int buf) {
        const int k0 = kt * 32;
#pragma unroll
        for (int ii = 0; ii < 2; ++ii) {
            int instr = wave * 2 + ii;           // 0..15, 1 KB each (16 rows)
            int row = instr * 16 + srow;         // tile row 0..255
            gload_lds16(A  + (m0 + row) * 512 + k0 + sgp * 8, &As[buf][instr * 512]);
            gload_lds16(Bw + (size_t)(n0 + row) * 512 + k0 + sgp * 8, &Bs[buf][instr * 512]);
        }
    };

    stage(0, 0); stage(1, 1); stage(2, 2);

    const int phr = (lg ^ (lr & 3)) * 8;         // read piece offset (elems)

    for (int kt = 0; kt < 16; ++kt) {
        const int cur = kt & 3;
        if (kt < 13) {
            stage(kt + 3, (kt + 3) & 3);
            asm volatile("s_waitcnt vmcnt(12)" ::: "memory");  // tile-kt loads done
        } else if (kt == 13) {
            asm volatile("s_waitcnt vmcnt(8)" ::: "memory");
        } else if (kt == 14) {
            asm volatile("s_waitcnt vmcnt(4)" ::: "memory");
        } else {
            asm volatile("s_waitcnt vmcnt(0)" ::: "memory");
        }
        __builtin_amdgcn_sched_barrier(0);
        __builtin_amdgcn_s_barrier();            // buf[cur] staged for all waves
        __builtin_amdgcn_sched_barrier(0);

        bf16x8_t af[8], bfr[4];
#pragma unroll
        for (int i = 0; i < 8; ++i)
            af[i] = *(const bf16x8_t*)&As[cur][(wr * 128 + i * 16 + lr) * 32 + phr];
#pragma unroll
        for (int j = 0; j < 4; ++j)
            bfr[j] = *(const bf16x8_t*)&Bs[cur][(wc * 64 + j * 16 + lr) * 32 + phr];

        __builtin_amdgcn_s_setprio(1);
#pragma unroll
        for (int i = 0; i < 8; ++i)
#pragma unroll
            for (int j = 0; j < 4; ++j)
                acc[i][j] = MFMA16(af[i], bfr[j], acc[i][j]);
        __builtin_amdgcn_s_setprio(0);

        asm volatile("s_waitcnt lgkmcnt(0)" ::: "memory");  // reads retired
        __builtin_amdgcn_sched_barrier(0);
        __builtin_amdgcn_s_barrier();            // safe to overwrite ring slot
        __builtin_amdgcn_sched_barrier(0);
    }

    // ---- epilogue: bias + head-major store ----------------------------------
    float bj[4];
#pragma unroll
    for (int j = 0; j < 4; ++j) bj[j] = bias[n0 + wc * 64 + j * 16 + lr];
#pragma unroll
    for (int i = 0; i < 8; ++i)
#pragma unroll
        for (int j = 0; j < 4; ++j) {
            int col   = n0 + wc * 64 + j * 16 + lr;    // 0..1535
            int which = col >> 9;
            int h     = (col >> 5) & 15;
            int d     = col & 31;
            bf16* base = Cq + (size_t)(which * 16 + h) * (512 * 2048);
#pragma unroll
            for (int r = 0; r < 4; ++r) {
                int mrow = (int)m0 + wr * 128 + i * 16 + lg * 4 + r;
                int win = mrow >> 6, tok = mrow & 63;  // win 0..511 local
                base[(size_t)win * 2048 + tok * 32 + d] = (bf16)(acc[i][j][r] + bj[j]);
            }
        }
}

// ---------------------------------------------------------------------------
// Kernel 4: window attention over one 512-window chunk. BARRIER-FREE.
// Pad 68 (was 72): 52.2 KB/block -> 3 blocks/CU (latency-bound kernel).
// ---------------------------------------------------------------------------
#define APAD 68
__global__ __launch_bounds__(256, 2) void k_attn(
    const bf16*  __restrict__ qkv,   // chunk head-major [3][16][512][64][32]
    const float* __restrict__ rpe,   // (16,64,64) f32
    const float* __restrict__ mask,  // (64,64,64) f32
    bf16* __restrict__ ao,           // (2048,64,512) bf16 (global rows)
    int winbase)                     // chunk * 512
{
    __shared__ bf16 vts[4][32 * APAD]; // per-wave v^T [32 d][64 tok pad]
    __shared__ bf16 ps[4][64 * APAD];  // per-wave P   [64 q ][64 tok pad]

    const int tid  = threadIdx.x;
    const int lane = tid & 63;
    const int wave = tid >> 6;
    const int lr   = lane & 15;
    const int lg   = lane >> 4;
    const int bw   = blockIdx.x;          // local window 0..511
    const int gw   = winbase + bw;        // global window
    const int wi   = gw & 63;             // mask index
    const float* mp = mask + (size_t)wi * 4096;
    bf16* pvt = &vts[wave][0];
    bf16* pps = &ps[wave][0];

    const float SCALE = 0.17677669529663687f;  // 32^-0.5

    for (int hh = 0; hh < 4; ++hh) {
        const int h  = wave * 4 + hh;
        const float* rp = rpe + (size_t)h * 4096;
        const bf16* qb = qkv + ((size_t)(h)      * 512 + bw) * 2048;
        const bf16* kb = qkv + ((size_t)(16 + h) * 512 + bw) * 2048;
        const bf16* vb = qkv + ((size_t)(32 + h) * 512 + bw) * 2048;

        bf16x8_t qf[4], kf[4];
#pragma unroll
        for (int t = 0; t < 4; ++t) {
            qf[t] = *(const bf16x8_t*)(qb + (t * 16 + lr) * 32 + lg * 8);
            kf[t] = *(const bf16x8_t*)(kb + (t * 16 + lr) * 32 + lg * 8);
        }
#pragma unroll
        for (int j = 0; j < 4; ++j) {
            bf16x8_t vr = *(const bf16x8_t*)(vb + (j * 16 + (lane >> 2)) * 32 + (lane & 3) * 8);
#pragma unroll
            for (int i = 0; i < 8; ++i)
                pvt[((lane & 3) * 8 + i) * APAD + j * 16 + (lane >> 2)] = vr[i];
        }

        float sminv[4][4];
#pragma unroll
        for (int mt = 0; mt < 4; ++mt) {
            f32x4_t s[4];
            f32x4_t zero = {};
#pragma unroll
            for (int nt = 0; nt < 4; ++nt)
                s[nt] = MFMA16(qf[mt], kf[nt], zero);
            float rm[4][4];
#pragma unroll
            for (int nt = 0; nt < 4; ++nt) {
                int col = nt * 16 + lr;
#pragma unroll
                for (int r = 0; r < 4; ++r) {
                    int rrow = mt * 16 + lg * 4 + r;
                    rm[nt][r] = rp[rrow * 64 + col] + mp[rrow * 64 + col];
                }
            }
            float mx[4] = {-1e30f, -1e30f, -1e30f, -1e30f};
#pragma unroll
            for (int nt = 0; nt < 4; ++nt)
#pragma unroll
                for (int r = 0; r < 4; ++r) {
                    float tv = s[nt][r] * SCALE + rm[nt][r];
                    s[nt][r] = tv;
                    mx[r] = fmaxf(mx[r], tv);
                }
#pragma unroll
            for (int r = 0; r < 4; ++r) {
                float m = mx[r];
                m = fmaxf(m, __shfl_xor(m, 1));
                m = fmaxf(m, __shfl_xor(m, 2));
                m = fmaxf(m, __shfl_xor(m, 4));
                m = fmaxf(m, __shfl_xor(m, 8));
                mx[r] = m;
            }
            float sm[4] = {0.f, 0.f, 0.f, 0.f};
#pragma unroll
            for (int nt = 0; nt < 4; ++nt)
#pragma unroll
                for (int r = 0; r < 4; ++r) {
                    float e = __expf(s[nt][r] - mx[r]);
                    s[nt][r] = e;
                    sm[r] += e;
                }
#pragma unroll
            for (int r = 0; r < 4; ++r) {
                float ssum = sm[r];
                ssum += __shfl_xor(ssum, 1);
                ssum += __shfl_xor(ssum, 2);
                ssum += __shfl_xor(ssum, 4);
                ssum += __shfl_xor(ssum, 8);
                sminv[mt][r] = 1.0f / ssum;
            }
#pragma unroll
            for (int nt = 0; nt < 4; ++nt)
#pragma unroll
                for (int r = 0; r < 4; ++r)
                    pps[(mt * 16 + lg * 4 + r) * APAD + nt * 16 + lr] = (bf16)s[nt][r];
        }

#pragma unroll
        for (int mt = 0; mt < 4; ++mt) {
            f32x4_t o[2] = {};
#pragma unroll
            for (int ks = 0; ks < 2; ++ks) {
                bf16x8_t pa = *(const bf16x8_t*)&pps[(mt * 16 + lr) * APAD + ks * 32 + lg * 8];
#pragma unroll
                for (int jd = 0; jd < 2; ++jd) {
                    bf16x8_t bv = *(const bf16x8_t*)&pvt[(jd * 16 + lr) * APAD + ks * 32 + lg * 8];
                    o[jd] = MFMA16(pa, bv, o[jd]);
                }
            }
#pragma unroll
            for (int jd = 0; jd < 2; ++jd)
#pragma unroll
                for (int r = 0; r < 4; ++r) {
                    size_t rrow = (size_t)gw * 64 + mt * 16 + lg * 4 + r;
                    ao[rrow * 512 + h * 32 + jd * 16 + lr] = (bf16)(o[jd][r] * sminv[mt][r]);
                }
        }
    }
}

// ---------------------------------------------------------------------------
// Kernel 5: proj GEMM, same 4-ring BK=32 skeleton. out = ao@proj_w^T + bias.
// ---------------------------------------------------------------------------
__global__ __launch_bounds__(512, 2) void k_proj(
    const bf16* __restrict__ A, const bf16* __restrict__ Bw,
    const float* __restrict__ bias, float* __restrict__ C)
{
    __shared__ bf16 As[4][256 * 32];
    __shared__ bf16 Bs[4][256 * 32];

    const int tid  = threadIdx.x;
    const int lane = tid & 63;
    const int wave = tid >> 6;
    const int lr = lane & 15, lg = lane >> 4;
    const int wr = wave >> 2, wc = wave & 3;
    const int bid = blockIdx.x;                  // 0..1023 (= 8 * 128)
    const int wg  = (bid & 7) * 128 + (bid >> 3);
    const int mb = wg >> 1, nb = wg & 1;         // 512 x 2
    const size_t m0 = (size_t)mb * 256;
    const int n0 = nb * 256;

    const int srow = lane >> 2;
    const int sgp  = (lane & 3) ^ (srow & 3);

    f32x4_t acc[8][4] = {};

    auto stage = [&](int kt, int buf) {
        const int k0 = kt * 32;
#pragma unroll
        for (int ii = 0; ii < 2; ++ii) {
            int instr = wave * 2 + ii;
            int row = instr * 16 + srow;
            gload_lds16(A  + (m0 + row) * 512 + k0 + sgp * 8, &As[buf][instr * 512]);
            gload_lds16(Bw + (size_t)(n0 + row) * 512 + k0 + sgp * 8, &Bs[buf][instr * 512]);
        }
    };

    stage(0, 0); stage(1, 1); stage(2, 2);

    const int phr = (lg ^ (lr & 3)) * 8;

    for (int kt = 0; kt < 16; ++kt) {
        const int cur = kt & 3;
        if (kt < 13) {
            stage(kt + 3, (kt + 3) & 3);
            asm volatile("s_waitcnt vmcnt(12)" ::: "memory");
        } else if (kt == 13) {
            asm volatile("s_waitcnt vmcnt(8)" ::: "memory");
        } else if (kt == 14) {
            asm volatile("s_waitcnt vmcnt(4)" ::: "memory");
        } else {
            asm volatile("s_waitcnt vmcnt(0)" ::: "memory");
        }
        __builtin_amdgcn_sched_barrier(0);
        __builtin_amdgcn_s_barrier();
        __builtin_amdgcn_sched_barrier(0);

        bf16x8_t af[8], bfr[4];
#pragma unroll
        for (int i = 0; i < 8; ++i)
            af[i] = *(const bf16x8_t*)&As[cur][(wr * 128 + i * 16 + lr) * 32 + phr];
#pragma unroll
        for (int j = 0; j < 4; ++j)
            bfr[j] = *(const bf16x8_t*)&Bs[cur][(wc * 64 + j * 16 + lr) * 32 + phr];

        __builtin_amdgcn_s_setprio(1);
#pragma unroll
        for (int i = 0; i < 8; ++i)
#pragma unroll
            for (int j = 0; j < 4; ++j)
                acc[i][j] = MFMA16(af[i], bfr[j], acc[i][j]);
        __builtin_amdgcn_s_setprio(0);

        asm volatile("s_waitcnt lgkmcnt(0)" ::: "memory");
        __builtin_amdgcn_sched_barrier(0);
        __builtin_amdgcn_s_barrier();
        __builtin_amdgcn_sched_barrier(0);
    }

    float bj[4];
#pragma unroll
    for (int j = 0; j < 4; ++j) bj[j] = bias[n0 + wc * 64 + j * 16 + lr];
#pragma unroll
    for (int i = 0; i < 8; ++i)
#pragma unroll
        for (int j = 0; j < 4; ++j) {
            int col = n0 + wc * 64 + j * 16 + lr;
#pragma unroll
            for (int r = 0; r < 4; ++r) {
                size_t rw = m0 + wr * 128 + i * 16 + lg * 4 + r;
                C[rw * 512 + col] = acc[i][j][r] + bj[j];
            }
        }
}

// ---------------------------------------------------------------------------
extern "C" void kernel_launch(void* const* d_in, const int* in_sizes, int n_in,
                              void* d_out, int out_size, void* d_ws, size_t ws_size,
                              hipStream_t stream) {
    (void)in_sizes; (void)n_in; (void)out_size; (void)ws_size;
    const float* x      = (const float*)d_in[0];
    const float* pe     = (const float*)d_in[1];
    const float* rpe    = (const float*)d_in[2];
    const float* mask   = (const float*)d_in[3];
    const float* qkv_w  = (const float*)d_in[4];
    const float* qkv_b  = (const float*)d_in[5];
    const float* proj_w = (const float*)d_in[6];
    const float* proj_b = (const float*)d_in[7];
    float* out = (float*)d_out;

    char* ws = (char*)d_ws;
    bf16* wqkvb  = (bf16*)ws;                    // 1,572,864 B
    bf16* wprojb = (bf16*)(ws + 1572864);        //   524,288 B
    bf16* ao     = (bf16*)(ws + 2097152);        // 134,217,728 B (ws total 136.3 MB)

    // d_out (256 MB) as scratch, dead before k_proj's final write:
    bf16* xp   = (bf16*)d_out;                         // 134,217,728 B
    bf16* qkvc = (bf16*)((char*)d_out + 134217728);    // 100,663,296 B (chunk)

    k_wprep<<<256, 256, 0, stream>>>(qkv_w, proj_w, wqkvb, wprojb);
    k_xprep<<<4096, 256, 0, stream>>>(x, pe, xp);
    for (int c = 0; c < 4; ++c) {
        k_qkv<<<768, 512, 0, stream>>>(xp + (size_t)c * 32768 * 512,
                                       wqkvb, qkv_b, qkvc);
        k_attn<<<512, 256, 0, stream>>>(qkvc, rpe, mask, ao, c * 512);
    }
    k_proj<<<1024, 512, 0, stream>>>(ao, wprojb, proj_b, out);
}

// Round 11
// 712.342 us; speedup vs baseline: 1.1611x; 1.1611x over previous
//
#include <hip/hip_runtime.h>
#include <hip/hip_bf16.h>
#include <cstdint>

// Problem: B_=2048 windows, N=64 tokens, C=512, H=16 heads, hd=32, nW=64.
// Pipeline: k_wprep, k_xprep -> 4x { k_qkv -> k_attn } -> k_proj.
// GEMMs: m97-recipe — 128^2 tile, BK=64, 4 waves, SINGLE-buffer 32KB LDS,
// gload_lds + XOR swizzle (r8-proven, 0 conflicts), plain __syncthreads(),
// ~88 VGPR -> 5 blocks/CU. Occupancy does the pipelining (m114/m97).
typedef __bf16 bf16;
typedef __bf16 bf16x8_t __attribute__((ext_vector_type(8)));
typedef __bf16 bf16x4_t __attribute__((ext_vector_type(4)));
typedef float  f32x4_t  __attribute__((ext_vector_type(4)));

#define MFMA16(a, b, c) __builtin_amdgcn_mfma_f32_16x16x32_bf16((a), (b), (c), 0, 0, 0)

__device__ __forceinline__ void gload_lds16(const bf16* g, bf16* l) {
    __builtin_amdgcn_global_load_lds(
        (const __attribute__((address_space(1))) void*)g,
        (__attribute__((address_space(3))) void*)l,
        16, 0, 0);
}

// ---------------------------------------------------------------------------
// Kernel 1: convert weights to bf16 (qkv_w 1536x512, proj_w 512x512)
// ---------------------------------------------------------------------------
__global__ void k_wprep(const float* __restrict__ wq, const float* __restrict__ wp,
                        bf16* __restrict__ wqb, bf16* __restrict__ wpb) {
    int t = blockIdx.x * 256 + threadIdx.x;
    int stride = gridDim.x * 256;
    for (int i = t; i < 196608; i += stride) {
        float4 v = ((const float4*)wq)[i];
        bf16x4_t o; o[0]=(bf16)v.x; o[1]=(bf16)v.y; o[2]=(bf16)v.z; o[3]=(bf16)v.w;
        ((bf16x4_t*)wqb)[i] = o;
    }
    for (int i = t; i < 65536; i += stride) {
        float4 v = ((const float4*)wp)[i];
        bf16x4_t o; o[0]=(bf16)v.x; o[1]=(bf16)v.y; o[2]=(bf16)v.z; o[3]=(bf16)v.w;
        ((bf16x4_t*)wpb)[i] = o;
    }
}

// ---------------------------------------------------------------------------
// Kernel 2: xp[131072][512] = bf16(x + pe)  (one shot, memory-bound)
// ---------------------------------------------------------------------------
__global__ void k_xprep(const float* __restrict__ x, const float* __restrict__ pe,
                        bf16* __restrict__ xp) {
    int t = blockIdx.x * 256 + threadIdx.x;
    int stride = gridDim.x * 256;
    for (int i = t; i < 8388608; i += stride) {
        int row = i >> 6;
        int g   = (i & 63) * 8;
        const float* xr = x  + ((size_t)row << 9) + g;
        const float* pr = pe + ((size_t)(row & 63) << 9) + g;
        float4 x0 = *(const float4*)(xr);
        float4 x1 = *(const float4*)(xr + 4);
        float4 p0 = *(const float4*)(pr);
        float4 p1 = *(const float4*)(pr + 4);
        bf16x8_t v;
        v[0]=(bf16)(x0.x+p0.x); v[1]=(bf16)(x0.y+p0.y);
        v[2]=(bf16)(x0.z+p0.z); v[3]=(bf16)(x0.w+p0.w);
        v[4]=(bf16)(x1.x+p1.x); v[5]=(bf16)(x1.y+p1.y);
        v[6]=(bf16)(x1.z+p1.z); v[7]=(bf16)(x1.w+p1.w);
        *(bf16x8_t*)(xp + (size_t)i * 8) = v;
    }
}

// ---------------------------------------------------------------------------
// Kernel 3: QKV GEMM over one 32768-row chunk. m97 recipe: 128x128, BK=64,
// 4 waves, single-buffer 32KB, gload_lds XOR-swizzled, __syncthreads only.
// Output head-major per chunk: [3][16][512 win][64 tok][32 d] bf16.
// ---------------------------------------------------------------------------
__global__ __launch_bounds__(256, 4) void k_qkv(
    const bf16*  __restrict__ A,     // chunk xp: (32768, 512) bf16
    const bf16*  __restrict__ Bw,    // (1536, 512) bf16
    const float* __restrict__ bias,  // (1536,) f32
    bf16* __restrict__ Cq)           // chunk out, head-major (100.7 MB)
{
    __shared__ bf16 As[128 * 64];    // 16 KB, linear, XOR-swizzled pieces
    __shared__ bf16 Bs[128 * 64];    // 16 KB
    // LDS 32,768 B -> 5 blocks/CU at <=102 VGPR (r8 measured 88)

    const int tid  = threadIdx.x;
    const int lane = tid & 63;
    const int wave = tid >> 6;
    const int lr = lane & 15, lg = lane >> 4;
    const int wr = wave >> 1, wc = wave & 1;
    const int bid = blockIdx.x;                   // 0..3071 (= 8 * 384)
    const int wg  = (bid & 7) * 384 + (bid >> 3); // XCD-contiguous chunks
    const int mb  = wg / 12, nb = wg - mb * 12;   // 256 x 12
    const size_t m0 = (size_t)mb * 128;
    const int n0 = nb * 128;

    f32x4_t acc[4][4] = {};

    for (int kt = 0; kt < 8; ++kt) {
        const int k0 = kt * 64;
        // stage: 32 x 1KB gload_lds (8 per wave), pre-swizzled source piece
#pragma unroll
        for (int ii = 0; ii < 4; ++ii) {
            int instr = wave * 4 + ii;           // 0..15 (8 rows each)
            int r  = instr * 8 + (lane >> 3);    // tile row 0..127
            int gp = (lane & 7) ^ (r & 7);
            gload_lds16(A  + (m0 + r) * 512 + k0 + gp * 8, &As[instr * 512]);
            gload_lds16(Bw + (size_t)(n0 + r) * 512 + k0 + gp * 8, &Bs[instr * 512]);
        }
        __syncthreads();                         // compiler emits vmcnt(0) drain

#pragma unroll
        for (int k2 = 0; k2 < 2; ++k2) {
            bf16x8_t af[4], bfr[4];
#pragma unroll
            for (int i = 0; i < 4; ++i) {
                int rowa = wr * 64 + i * 16 + lr;
                int ph   = (k2 * 4 + lg) ^ (rowa & 7);
                af[i] = *(const bf16x8_t*)&As[rowa * 64 + ph * 8];
            }
#pragma unroll
            for (int j = 0; j < 4; ++j) {
                int rowb = wc * 64 + j * 16 + lr;
                int ph   = (k2 * 4 + lg) ^ (rowb & 7);
                bfr[j] = *(const bf16x8_t*)&Bs[rowb * 64 + ph * 8];
            }
#pragma unroll
            for (int i = 0; i < 4; ++i)
#pragma unroll
                for (int j = 0; j < 4; ++j)
                    acc[i][j] = MFMA16(af[i], bfr[j], acc[i][j]);
        }
        __syncthreads();                         // reads done before re-stage
    }

    // ---- epilogue: bias + head-major store ----------------------------------
    float bj[4];
#pragma unroll
    for (int j = 0; j < 4; ++j) bj[j] = bias[n0 + wc * 64 + j * 16 + lr];
#pragma unroll
    for (int i = 0; i < 4; ++i)
#pragma unroll
        for (int j = 0; j < 4; ++j) {
            int col   = n0 + wc * 64 + j * 16 + lr;    // 0..1535
            int which = col >> 9;
            int h     = (col >> 5) & 15;
            int d     = col & 31;
            bf16* base = Cq + (size_t)(which * 16 + h) * (512 * 2048);
#pragma unroll
            for (int r = 0; r < 4; ++r) {
                int mrow = (int)m0 + wr * 64 + i * 16 + lg * 4 + r;
                int win = mrow >> 6, tok = mrow & 63;  // win 0..511 local
                base[(size_t)win * 2048 + tok * 32 + d] = (bf16)(acc[i][j][r] + bj[j]);
            }
        }
}

// ---------------------------------------------------------------------------
// Kernel 4: window attention over one 512-window chunk (r9 verbatim).
// BARRIER-FREE: each wave owns (window, 4 heads), private vts/ps LDS.
// ---------------------------------------------------------------------------
__global__ __launch_bounds__(256, 2) void k_attn(
    const bf16*  __restrict__ qkv,   // chunk head-major [3][16][512][64][32]
    const float* __restrict__ rpe,   // (16,64,64) f32
    const float* __restrict__ mask,  // (64,64,64) f32
    bf16* __restrict__ ao,           // (2048,64,512) bf16 (global rows)
    int winbase)                     // chunk * 512
{
    __shared__ bf16 vts[4][32 * 72]; // per-wave v^T [32 d][64 tok pad 72]
    __shared__ bf16 ps[4][64 * 72];  // per-wave P   [64 q ][64 tok pad 72]

    const int tid  = threadIdx.x;
    const int lane = tid & 63;
    const int wave = tid >> 6;
    const int lr   = lane & 15;
    const int lg   = lane >> 4;
    const int bw   = blockIdx.x;          // local window 0..511
    const int gw   = winbase + bw;        // global window
    const int wi   = gw & 63;             // mask index
    const float* mp = mask + (size_t)wi * 4096;
    bf16* pvt = &vts[wave][0];
    bf16* pps = &ps[wave][0];

    const float SCALE = 0.17677669529663687f;  // 32^-0.5

    for (int hh = 0; hh < 4; ++hh) {
        const int h  = wave * 4 + hh;
        const float* rp = rpe + (size_t)h * 4096;
        const bf16* qb = qkv + ((size_t)(h)      * 512 + bw) * 2048;
        const bf16* kb = qkv + ((size_t)(16 + h) * 512 + bw) * 2048;
        const bf16* vb = qkv + ((size_t)(32 + h) * 512 + bw) * 2048;

        bf16x8_t qf[4], kf[4];
#pragma unroll
        for (int t = 0; t < 4; ++t) {
            qf[t] = *(const bf16x8_t*)(qb + (t * 16 + lr) * 32 + lg * 8);
            kf[t] = *(const bf16x8_t*)(kb + (t * 16 + lr) * 32 + lg * 8);
        }
#pragma unroll
        for (int j = 0; j < 4; ++j) {
            bf16x8_t vr = *(const bf16x8_t*)(vb + (j * 16 + (lane >> 2)) * 32 + (lane & 3) * 8);
#pragma unroll
            for (int i = 0; i < 8; ++i)
                pvt[((lane & 3) * 8 + i) * 72 + j * 16 + (lane >> 2)] = vr[i];
        }

        float sminv[4][4];
#pragma unroll
        for (int mt = 0; mt < 4; ++mt) {
            f32x4_t s[4];
            f32x4_t zero = {};
#pragma unroll
            for (int nt = 0; nt < 4; ++nt)
                s[nt] = MFMA16(qf[mt], kf[nt], zero);
            float rm[4][4];
#pragma unroll
            for (int nt = 0; nt < 4; ++nt) {
                int col = nt * 16 + lr;
#pragma unroll
                for (int r = 0; r < 4; ++r) {
                    int rrow = mt * 16 + lg * 4 + r;
                    rm[nt][r] = rp[rrow * 64 + col] + mp[rrow * 64 + col];
                }
            }
            float mx[4] = {-1e30f, -1e30f, -1e30f, -1e30f};
#pragma unroll
            for (int nt = 0; nt < 4; ++nt)
#pragma unroll
                for (int r = 0; r < 4; ++r) {
                    float tv = s[nt][r] * SCALE + rm[nt][r];
                    s[nt][r] = tv;
                    mx[r] = fmaxf(mx[r], tv);
                }
#pragma unroll
            for (int r = 0; r < 4; ++r) {
                float m = mx[r];
                m = fmaxf(m, __shfl_xor(m, 1));
                m = fmaxf(m, __shfl_xor(m, 2));
                m = fmaxf(m, __shfl_xor(m, 4));
                m = fmaxf(m, __shfl_xor(m, 8));
                mx[r] = m;
            }
            float sm[4] = {0.f, 0.f, 0.f, 0.f};
#pragma unroll
            for (int nt = 0; nt < 4; ++nt)
#pragma unroll
                for (int r = 0; r < 4; ++r) {
                    float e = __expf(s[nt][r] - mx[r]);
                    s[nt][r] = e;
                    sm[r] += e;
                }
#pragma unroll
            for (int r = 0; r < 4; ++r) {
                float ssum = sm[r];
                ssum += __shfl_xor(ssum, 1);
                ssum += __shfl_xor(ssum, 2);
                ssum += __shfl_xor(ssum, 4);
                ssum += __shfl_xor(ssum, 8);
                sminv[mt][r] = 1.0f / ssum;
            }
#pragma unroll
            for (int nt = 0; nt < 4; ++nt)
#pragma unroll
                for (int r = 0; r < 4; ++r)
                    pps[(mt * 16 + lg * 4 + r) * 72 + nt * 16 + lr] = (bf16)s[nt][r];
        }

#pragma unroll
        for (int mt = 0; mt < 4; ++mt) {
            f32x4_t o[2] = {};
#pragma unroll
            for (int ks = 0; ks < 2; ++ks) {
                bf16x8_t pa = *(const bf16x8_t*)&pps[(mt * 16 + lr) * 72 + ks * 32 + lg * 8];
#pragma unroll
                for (int jd = 0; jd < 2; ++jd) {
                    bf16x8_t bv = *(const bf16x8_t*)&pvt[(jd * 16 + lr) * 72 + ks * 32 + lg * 8];
                    o[jd] = MFMA16(pa, bv, o[jd]);
                }
            }
#pragma unroll
            for (int jd = 0; jd < 2; ++jd)
#pragma unroll
                for (int r = 0; r < 4; ++r) {
                    size_t rrow = (size_t)gw * 64 + mt * 16 + lg * 4 + r;
                    ao[rrow * 512 + h * 32 + jd * 16 + lr] = (bf16)(o[jd][r] * sminv[mt][r]);
                }
        }
    }
}

// ---------------------------------------------------------------------------
// Kernel 5: proj GEMM, same m97 recipe. out[131072,512] = ao@proj_w^T + bias.
// ---------------------------------------------------------------------------
__global__ __launch_bounds__(256, 4) void k_proj(
    const bf16* __restrict__ A, const bf16* __restrict__ Bw,
    const float* __restrict__ bias, float* __restrict__ C)
{
    __shared__ bf16 As[128 * 64];
    __shared__ bf16 Bs[128 * 64];

    const int tid  = threadIdx.x;
    const int lane = tid & 63;
    const int wave = tid >> 6;
    const int lr = lane & 15, lg = lane >> 4;
    const int wr = wave >> 1, wc = wave & 1;
    const int bid = blockIdx.x;                  // 0..4095
    const int wg  = (bid & 7) * 512 + (bid >> 3);
    const int mb = wg >> 2, nb = wg & 3;
    const size_t m0 = (size_t)mb * 128;
    const int n0 = nb * 128;

    f32x4_t acc[4][4] = {};

    for (int kt = 0; kt < 8; ++kt) {
        const int k0 = kt * 64;
#pragma unroll
        for (int ii = 0; ii < 4; ++ii) {
            int instr = wave * 4 + ii;
            int r  = instr * 8 + (lane >> 3);
            int gp = (lane & 7) ^ (r & 7);
            gload_lds16(A  + (m0 + r) * 512 + k0 + gp * 8, &As[instr * 512]);
            gload_lds16(Bw + (size_t)(n0 + r) * 512 + k0 + gp * 8, &Bs[instr * 512]);
        }
        __syncthreads();

#pragma unroll
        for (int k2 = 0; k2 < 2; ++k2) {
            bf16x8_t af[4], bfr[4];
#pragma unroll
            for (int i = 0; i < 4; ++i) {
                int rowa = wr * 64 + i * 16 + lr;
                int ph   = (k2 * 4 + lg) ^ (rowa & 7);
                af[i] = *(const bf16x8_t*)&As[rowa * 64 + ph * 8];
            }
#pragma unroll
            for (int j = 0; j < 4; ++j) {
                int rowb = wc * 64 + j * 16 + lr;
                int ph   = (k2 * 4 + lg) ^ (rowb & 7);
                bfr[j] = *(const bf16x8_t*)&Bs[rowb * 64 + ph * 8];
            }
#pragma unroll
            for (int i = 0; i < 4; ++i)
#pragma unroll
                for (int j = 0; j < 4; ++j)
                    acc[i][j] = MFMA16(af[i], bfr[j], acc[i][j]);
        }
        __syncthreads();
    }

    float bj[4];
#pragma unroll
    for (int j = 0; j < 4; ++j) bj[j] = bias[n0 + wc * 64 + j * 16 + lr];
#pragma unroll
    for (int i = 0; i < 4; ++i)
#pragma unroll
        for (int j = 0; j < 4; ++j) {
            int col = n0 + wc * 64 + j * 16 + lr;
#pragma unroll
            for (int r = 0; r < 4; ++r) {
                size_t rw = m0 + wr * 64 + i * 16 + lg * 4 + r;
                C[rw * 512 + col] = acc[i][j][r] + bj[j];
            }
        }
}

// ---------------------------------------------------------------------------
extern "C" void kernel_launch(void* const* d_in, const int* in_sizes, int n_in,
                              void* d_out, int out_size, void* d_ws, size_t ws_size,
                              hipStream_t stream) {
    (void)in_sizes; (void)n_in; (void)out_size; (void)ws_size;
    const float* x      = (const float*)d_in[0];
    const float* pe     = (const float*)d_in[1];
    const float* rpe    = (const float*)d_in[2];
    const float* mask   = (const float*)d_in[3];
    const float* qkv_w  = (const float*)d_in[4];
    const float* qkv_b  = (const float*)d_in[5];
    const float* proj_w = (const float*)d_in[6];
    const float* proj_b = (const float*)d_in[7];
    float* out = (float*)d_out;

    char* ws = (char*)d_ws;
    bf16* wqkvb  = (bf16*)ws;                    // 1,572,864 B
    bf16* wprojb = (bf16*)(ws + 1572864);        //   524,288 B
    bf16* ao     = (bf16*)(ws + 2097152);        // 134,217,728 B (ws total 136.3 MB)

    // d_out (256 MB) as scratch, dead before k_proj's final write:
    bf16* xp   = (bf16*)d_out;                         // 134,217,728 B
    bf16* qkvc = (bf16*)((char*)d_out + 134217728);    // 100,663,296 B (chunk)

    k_wprep<<<256, 256, 0, stream>>>(qkv_w, proj_w, wqkvb, wprojb);
    k_xprep<<<4096, 256, 0, stream>>>(x, pe, xp);
    for (int c = 0; c < 4; ++c) {
        k_qkv<<<3072, 256, 0, stream>>>(xp + (size_t)c * 32768 * 512,
                                        wqkvb, qkv_b, qkvc);
        k_attn<<<512, 256, 0, stream>>>(qkvc, rpe, mask, ao, c * 512);
    }
    k_proj<<<4096, 256, 0, stream>>>(ao, wprojb, proj_b, out);
}